// Round 15
// baseline (262.993 us; speedup 1.0000x reference)
//
#include <hip/hip_runtime.h>
#include <hip/hip_bf16.h>

#define DEV __device__ __forceinline__

constexpr int N_ = 25000;
constexpr int P_ = 400000;

// ---------------- ws layout (units of 4 bytes) ----------------
constexpr int align4(int xx){ return (xx+3)&~3; }
constexpr int OFF_CNT     = 0;                          // N ints
constexpr int OFF_OFFSETS = align4(OFF_CNT + N_);       // N+1 ints
constexpr int OFF_CURSOR  = align4(OFF_OFFSETS + N_ + 1); // (unused since r11)
constexpr int OFF_EDGE    = align4(OFF_CURSOR + N_);    // P*16 dwords (32 bf16 edge feats, sorted order)
constexpr int OFF_E4      = OFF_EDGE + P_*16;           // P*4  f32
constexpr int OFF_DIR     = OFF_E4 + P_*4;              // P*4  f32 (written by k_edge2, coalesced)
constexpr int OFF_SEM     = align4(OFF_DIR + P_*4);     // N*64 dw  (bf16 sem, 128 cols)
constexpr int OFF_N2      = OFF_SEM + N_*64;            // N*16 dw  (bf16 n2, 32 cols)
constexpr int OFF_DV      = OFF_N2 + N_*16;             // N*4 f32
constexpr int OFF_WB5     = OFF_DV + N_*4;              // 1024 dw (frag order)
constexpr int OFF_WB6     = OFF_WB5 + 1024;             // 2048 dw
constexpr int OFF_WB7     = OFF_WB6 + 2048;             // 8192 dw
constexpr int OFF_WB8     = OFF_WB7 + 8192;             // 2048 dw
constexpr int OFF_WB9     = OFF_WB8 + 2048;             // 2048 dw
constexpr int OFF_HB      = OFF_WB9 + 2048;             // h as bf16: N*32 dw
constexpr int OFF_SIJ     = OFF_HB + N_*32;             // sorted (i,j) pairs: P*2 ints
constexpr int OFF_WB1     = OFF_SIJ + P_*2;             // 8192 dw (frag order)
constexpr int OFF_WB2     = OFF_WB1 + 8192;             // 2048 dw
constexpr int OFF_WB3     = OFF_WB2 + 2048;             // 1024 dw
constexpr int OFF_WB4     = OFF_WB3 + 1024;             // 2048 dw (frag order + logical col permute)
constexpr int OFF_RANK    = OFF_WB4 + 2048;             // P ints: edge rank within node (r11)
constexpr int WS_UNITS    = OFF_RANK + P_;

// PhysNet RBF constants (K=50, r_max=0.5)
constexpr float MU0F  = 0.60653065971263342f;               // exp(-0.5)
constexpr float DMUF  = (1.0f - 0.60653065971263342f) / 49.0f;
constexpr float BETAF = 1.0f / ((0.04f * (1.0f - 0.60653065971263342f)) *
                                (0.04f * (1.0f - 0.60653065971263342f)));
constexpr float EPSF  = 1e-8f;

DEV float u2f(unsigned int u){ union{unsigned int i; float f;} c; c.i=u; return c.f; }
DEV unsigned int f2b16(float f){
  __hip_bfloat16 b = __float2bfloat16(f);
  unsigned short s; __builtin_memcpy(&s, &b, 2);
  return (unsigned int)s;
}
DEV unsigned int pack2(float a, float b){ return f2b16(a) | (f2b16(b) << 16); }
// v_rcp_f32 (~1 ulp) instead of IEEE div; negligible vs bf16 rounding.
DEV float frcp(float x){ return __builtin_amdgcn_rcpf(x); }
DEV float silu_f(float v){ return v * frcp(1.0f + __expf(-v)); }

using short8 = __attribute__((ext_vector_type(8))) short;   // 8 bf16 (4 VGPRs)
using f32x4  = __attribute__((ext_vector_type(4))) float;
union U4S8 { uint4 u; short8 s; };
DEV short8 ld_frag(const void* p){ U4S8 c; c.u = *(const uint4*)p; return c.s; }
DEV f32x4 mfma16(short8 a, short8 b, f32x4 c){
  return __builtin_amdgcn_mfma_f32_16x16x32_bf16(a, b, c, 0, 0, 0);
}

// ---------------- hist (r11): histogram + RANK CAPTURE ----------------
__global__ void k_hist(const int* __restrict__ idx_i,
                       int* __restrict__ cnt, int* __restrict__ rank){
  int t = blockIdx.x*256 + threadIdx.x;
  if (t < P_) rank[t] = atomicAdd(&cnt[idx_i[t]], 1);
}

// ---------------- scan v3 (r11): block 0 scans; blocks 1..N transpose --------------
__global__ __launch_bounds__(1024) void k_scan2(
    const int* __restrict__ cnt, int* __restrict__ offsets,
    const float* __restrict__ h,
    const float* __restrict__ Wein, const float* __restrict__ Weo1,
    const float* __restrict__ Weo2, const float* __restrict__ Wxm,
    const float* __restrict__ Wpn1, const float* __restrict__ Wpn2,
    const float* __restrict__ Wn1,  const float* __restrict__ Wn2,
    const float* __restrict__ Wv1,
    unsigned int* __restrict__ hb,
    unsigned short* __restrict__ wb1, unsigned short* __restrict__ wb2,
    unsigned short* __restrict__ wb3, unsigned short* __restrict__ wb4,
    unsigned short* __restrict__ wb5, unsigned short* __restrict__ wb6,
    unsigned short* __restrict__ wb7, unsigned short* __restrict__ wb8,
    unsigned short* __restrict__ wb9){
  __shared__ unsigned short sCnt[N_];   // 50 KB (block 0 only touches it)
  __shared__ int swv[16];
  if (blockIdx.x == 0){
    const int t = threadIdx.x;
    const int wv = t >> 6, ln = t & 63;
    for (int q = t; q < N_; q += 1024) sCnt[q] = (unsigned short)cnt[q];
    __syncthreads();
    constexpr int CH = (N_ + 1023)/1024;   // 25
    int b = t*CH, e = b+CH;
    if (b > N_) b = N_;
    if (e > N_) e = N_;
    int s = 0;
    for (int q=b; q<e; q++) s += sCnt[q];
    int incl = s;
    #pragma unroll
    for (int off=1; off<64; off<<=1){
      int vv = __shfl_up(incl, off);
      if (ln >= off) incl += vv;
    }
    if (ln == 63) swv[wv] = incl;
    __syncthreads();
    if (wv == 0 && ln < 16){
      int w = swv[ln];
      #pragma unroll
      for (int off=1; off<16; off<<=1){
        int vv = __shfl_up(w, off);
        if (ln >= off) w += vv;
      }
      swv[ln] = w;
    }
    __syncthreads();
    const int wpre = (wv > 0) ? swv[wv-1] : 0;
    int run = wpre + incl - s;
    for (int q=b; q<e; q++){ offsets[q] = run; run += sCnt[q]; }
    if (t == 1023) offsets[N_] = run;
    return;
  }
  // ---- blocks 1..gridDim-1: hb conversion + frag-ordered weight transposes ----
  int t = (blockIdx.x-1)*1024 + threadIdx.x;
  const int st = (gridDim.x-1)*1024;
  for (int q=t; q<N_*32; q+=st){
    float2 a = *(const float2*)(h + (size_t)q*2);
    hb[q] = pack2(a.x, a.y);
  }
  // wb1: nf 0..7 (n=16nf+l15 over 0..127), s 0..3 (K=128)
  for (int q=t; q<8*4*64*8; q+=st){
    int e=q&7, lane=(q>>3)&63, sx=(q>>9)&3, nf=q>>11;
    int l15=lane&15, quad=lane>>4;
    int n = 16*nf + l15, k = sx*32 + quad*8 + e;
    float v = (n<50) ? Wein[k*50+n] : ((n<64) ? 0.f : Weo1[k*64+(n-64)]);
    wb1[q] = (unsigned short)f2b16(v);
  }
  // wb2: nf 0..3, s 0..1 (K=64); k<50 -> Weo1[128+k], k==50 -> Weo1[178], else 0
  for (int q=t; q<4*2*64*8; q+=st){
    int e=q&7, lane=(q>>3)&63, sx=(q>>9)&1, nf=q>>10;
    int l15=lane&15, quad=lane>>4;
    int n = 16*nf + l15, k = sx*32 + quad*8 + e;
    float v = (k<50) ? Weo1[(128+k)*64+n] : ((k==50) ? Weo1[178*64+n] : 0.f);
    wb2[q] = (unsigned short)f2b16(v);
  }
  // wb3: nf 0..1, s 0..1
  for (int q=t; q<2*2*64*8; q+=st){
    int e=q&7, lane=(q>>3)&63, sx=(q>>9)&1, nf=q>>10;
    int l15=lane&15, quad=lane>>4;
    int n = 16*nf + l15, k = sx*32 + quad*8 + e;
    wb3[q] = (unsigned short)f2b16(Weo2[k*32+n]);
  }
  // wb4: nf 0..7, K=32; physical n=16nf+l15 holds logical n_log=l15*8+nf
  for (int q=t; q<8*64*8; q+=st){
    int e=q&7, lane=(q>>3)&63, nf=q>>9;
    int l15=lane&15, quad=lane>>4;
    int k = quad*8 + e;
    int n_log = l15*8 + nf;
    int cc = n_log>>2, hh = n_log&3;
    wb4[q] = (unsigned short)f2b16(Wxm[(k*4+hh)*32 + cc]);
  }
  // wb5: nf 0..3, K=32
  for (int q=t; q<4*64*8; q+=st){
    int e=q&7, lane=(q>>3)&63, nf=q>>9;
    int l15=lane&15, quad=lane>>4;
    int n = 16*nf + l15, k = quad*8 + e;
    wb5[q] = (unsigned short)f2b16(Wpn1[k*64+n]);
  }
  // wb6 / wb8 / wb9: nf 0..3, s 0..1 (64x64 mats)
  for (int q=t; q<4*2*64*8; q+=st){
    int e=q&7, lane=(q>>3)&63, sx=(q>>9)&1, nf=q>>10;
    int l15=lane&15, quad=lane>>4;
    int n = 16*nf + l15, k = sx*32 + quad*8 + e;
    wb6[q] = (unsigned short)f2b16(Wpn2[k*64+n]);
    wb8[q] = (unsigned short)f2b16(Wn2[k*64+n]);
    wb9[q] = (unsigned short)f2b16(Wv1[k*64+n]);
  }
  // wb7: nf 0..3, s 0..7 (K=256)
  for (int q=t; q<4*8*64*8; q+=st){
    int e=q&7, lane=(q>>3)&63, sx=(q>>9)&7, nf=q>>12;
    int l15=lane&15, quad=lane>>4;
    int n = 16*nf + l15, k = sx*32 + quad*8 + e;
    wb7[q] = (unsigned short)f2b16(Wn1[k*64+n]);
  }
}

// ---------------- scatter v4 (r11): ATOMIC-FREE ----------------
__global__ void k_scatter3(const int* __restrict__ idx_i, const int* __restrict__ idx_j,
                           const int* __restrict__ offsets, const int* __restrict__ rank,
                           int* __restrict__ sij){
  int t = blockIdx.x*256 + threadIdx.x;
  if (t >= P_) return;
  int i = idx_i[t], j = idx_j[t];
  int pos = offsets[i] + rank[t];
  *(int2*)(sij + (size_t)pos*2) = make_int2(i, j);
}

// ---------------- MFMA edge kernel (r11 proven: ~54 us) ----------------
// r12 lesson: widening to 64 edges/wave made the allocator clamp at 88 VGPR
// (live set >=128) and reload A-frags between phases -> 73.7us. This 32-edge
// interleaved form is the structure's local optimum. Do not widen.
__global__ __launch_bounds__(256, 4) void k_edge2(
    const unsigned short* __restrict__ hb,
    const int* __restrict__ sij, const float* __restrict__ x,
    float* __restrict__ dir4,
    const unsigned short* __restrict__ wb1, const unsigned short* __restrict__ wb2,
    const unsigned short* __restrict__ wb3,
    const float* __restrict__ bein, const float* __restrict__ beo1,
    const float* __restrict__ beo2, const float* __restrict__ Watt,
    const float* __restrict__ batt,
    unsigned int* __restrict__ edge_out, float* __restrict__ e4_out)
{
  __shared__ __align__(16) unsigned char sAll[4*4608];   // 18432 B (1 scratch/wave)
  __shared__ float sdv[128];
  __shared__ float semd[128];

  const int tid  = threadIdx.x;
  const int wv   = tid >> 6;
  const int lane = tid & 63;
  const int l15  = lane & 15;
  const int quad = lane >> 4;
  const int pbase = blockIdx.x * 128;
  unsigned char* sW = sAll + wv*4608;

  // ---- geometry: sij coalesced read, x gathers (L2-hit), dir4 coalesced write ----
  if (lane < 32){
    int row = 32*wv + lane;
    int2 ij = *(const int2*)(sij + (size_t)(pbase + row)*2);
    float xi0=x[ij.x*3], xi1=x[ij.x*3+1], xi2=x[ij.x*3+2];
    float xj0=x[ij.y*3], xj1=x[ij.y*3+1], xj2=x[ij.y*3+2];
    float rx=xj0-xi0, ry=xj1-xi1, rz=xj2-xi2;
    float d = sqrtf(rx*rx+ry*ry+rz*rz+EPSF);
    float iv = frcp(d+EPSF);
    sdv[row]  = d;
    semd[row] = __expf(-d);
    *(float4*)(dir4 + (size_t)(pbase + row)*4) = make_float4(rx*iv, ry*iv, rz*iv, d);
  }

  // ---- A-fragments straight from global hb (row = 128 B of bf16) ----
  short8 af0[4], af1[4];
  {
    const int rbase = pbase + 32*wv;
    int2 ij0 = *(const int2*)(sij + (size_t)(rbase + l15)*2);
    int2 ij1 = *(const int2*)(sij + (size_t)(rbase + 16 + l15)*2);
    const unsigned char* hB = (const unsigned char*)hb;
    af0[0] = ld_frag(hB + (size_t)ij0.x*128 + quad*16);
    af0[1] = ld_frag(hB + (size_t)ij0.x*128 + 64 + quad*16);
    af0[2] = ld_frag(hB + (size_t)ij0.y*128 + quad*16);
    af0[3] = ld_frag(hB + (size_t)ij0.y*128 + 64 + quad*16);
    af1[0] = ld_frag(hB + (size_t)ij1.x*128 + quad*16);
    af1[1] = ld_frag(hB + (size_t)ij1.x*128 + 64 + quad*16);
    af1[2] = ld_frag(hB + (size_t)ij1.y*128 + quad*16);
    af1[3] = ld_frag(hB + (size_t)ij1.y*128 + 64 + quad*16);
  }

  // ---- GEMM-1a: [32 x 128] @ WB1[nf 0..3] (Wein) ----
  f32x4 acc[2][4];
  #pragma unroll
  for (int mf=0; mf<2; mf++)
    #pragma unroll
    for (int nf=0; nf<4; nf++){
      int nn = 16*nf + l15;
      float bias = (nn < 50) ? bein[nn] : 0.f;
      acc[mf][nf] = (f32x4){bias, bias, bias, bias};
    }
  #pragma unroll
  for (int s=0; s<4; s++){
    #pragma unroll
    for (int nf=0; nf<4; nf++){
      short8 b = ld_frag((const unsigned char*)wb1 + (size_t)((nf*4 + s)*64 + lane)*16);
      acc[0][nf] = mfma16(af0[s], b, acc[0][nf]);
      acc[1][nf] = mfma16(af1[s], b, acc[1][nf]);
    }
  }

  // ---- epilogue 1: RBF -> A2 bf16 [lrow][72 ushort] at sW ----
  #pragma unroll
  for (int mf=0; mf<2; mf++)
    #pragma unroll
    for (int nf=0; nf<4; nf++){
      int n = 16*nf + l15;
      float mu = MU0F + (float)n*DMUF;
      #pragma unroll
      for (int reg=0; reg<4; reg++){
        int lrow = 16*mf + quad*4 + reg;
        int grow = 32*wv + lrow;
        float t = semd[grow] - mu;
        float fv = acc[mf][nf][reg] * __expf(-BETAF*t*t);
        unsigned short ob;
        if (n < 50)       ob = (unsigned short)f2b16(fv);
        else if (n == 50) ob = (unsigned short)f2b16(sdv[grow]);
        else              ob = 0;
        ((unsigned short*)sW)[lrow*72 + n] = ob;
      }
    }

  // ---- GEMM-1b: @ WB1[nf 4..7] (Weo1-top) into reused acc ----
  #pragma unroll
  for (int mf=0; mf<2; mf++)
    #pragma unroll
    for (int nf=0; nf<4; nf++){
      float bias = beo1[16*nf + l15];
      acc[mf][nf] = (f32x4){bias, bias, bias, bias};
    }
  #pragma unroll
  for (int s=0; s<4; s++){
    #pragma unroll
    for (int nf=0; nf<4; nf++){
      short8 b = ld_frag((const unsigned char*)wb1 + (size_t)(((4+nf)*4 + s)*64 + lane)*16);
      acc[0][nf] = mfma16(af0[s], b, acc[0][nf]);
      acc[1][nf] = mfma16(af1[s], b, acc[1][nf]);
    }
  }

  // ---- GEMM-2: += A2 [32 x 64] @ WB2 [64 x 64] ----
  #pragma unroll
  for (int s=0; s<2; s++){
    int koff = s*32 + quad*8;
    short8 a0 = ld_frag(sW + l15*144      + koff*2);
    short8 a1 = ld_frag(sW + (16+l15)*144 + koff*2);
    #pragma unroll
    for (int nf=0; nf<4; nf++){
      short8 b = ld_frag((const unsigned char*)wb2 + (size_t)((nf*2 + s)*64 + lane)*16);
      acc[0][nf] = mfma16(a0, b, acc[0][nf]);
      acc[1][nf] = mfma16(a1, b, acc[1][nf]);
    }
  }

  // ---- epilogue 2: silu -> A3 bf16, OVERWRITING the A2 scratch (in-order DS) ----
  unsigned char* A3 = sW;
  #pragma unroll
  for (int mf=0; mf<2; mf++)
    #pragma unroll
    for (int nf=0; nf<4; nf++){
      int n = 16*nf + l15;
      #pragma unroll
      for (int reg=0; reg<4; reg++){
        int lrow = 16*mf + quad*4 + reg;
        ((unsigned short*)A3)[lrow*72 + n] = (unsigned short)f2b16(silu_f(acc[mf][nf][reg]));
      }
    }

  // ---- GEMM-3: [32 x 64] @ WB3 [64 x 32] ----
  f32x4 acc3[2][2];
  #pragma unroll
  for (int mf=0; mf<2; mf++)
    #pragma unroll
    for (int nf=0; nf<2; nf++){
      float bias = beo2[16*nf + l15];
      acc3[mf][nf] = (f32x4){bias, bias, bias, bias};
    }
  #pragma unroll
  for (int s=0; s<2; s++){
    int koff = s*32 + quad*8;
    short8 a0 = ld_frag(A3 + l15*144      + koff*2);
    short8 a1 = ld_frag(A3 + (16+l15)*144 + koff*2);
    #pragma unroll
    for (int nf=0; nf<2; nf++){
      short8 b = ld_frag((const unsigned char*)wb3 + (size_t)((nf*2 + s)*64 + lane)*16);
      acc3[0][nf] = mfma16(a0, b, acc3[0][nf]);
      acc3[1][nf] = mfma16(a1, b, acc3[1][nf]);
    }
  }

  // ---- epilogue 3: C3 f32 [lrow][36 f32], again overwriting the scratch ----
  #pragma unroll
  for (int mf=0; mf<2; mf++)
    #pragma unroll
    for (int nf=0; nf<2; nf++){
      int n = 16*nf + l15;
      #pragma unroll
      for (int reg=0; reg<4; reg++){
        int lrow = 16*mf + quad*4 + reg;
        ((float*)sW)[lrow*36 + n] = acc3[mf][nf][reg];
      }
    }

  // ---- attention + stores (2 lanes per row) ----
  {
    int rr = lane >> 1;
    int p = pbase + 32*wv + rr;
    int cb = (lane & 1) * 16;
    const float* er = (const float*)(sW + rr*144);
    float l0, l1, l2, l3;
    if ((lane & 1) == 0){ l0 = batt[0]; l1 = batt[1]; l2 = batt[2]; l3 = batt[3]; }
    else                { l0 = l1 = l2 = l3 = 0.f; }
    float ecache[16];
    {
      float4 v0 = *(const float4*)(er + cb);
      float4 v1 = *(const float4*)(er + cb + 4);
      float4 v2 = *(const float4*)(er + cb + 8);
      float4 v3 = *(const float4*)(er + cb + 12);
      ecache[0]=v0.x; ecache[1]=v0.y; ecache[2]=v0.z; ecache[3]=v0.w;
      ecache[4]=v1.x; ecache[5]=v1.y; ecache[6]=v1.z; ecache[7]=v1.w;
      ecache[8]=v2.x; ecache[9]=v2.y; ecache[10]=v2.z; ecache[11]=v2.w;
      ecache[12]=v3.x; ecache[13]=v3.y; ecache[14]=v3.z; ecache[15]=v3.w;
    }
    #pragma unroll
    for (int c=0;c<16;c++){
      float ev = ecache[c];
      const float4 wr = *(const float4*)(Watt + (cb + c)*4);
      l0 += ev*wr.x; l1 += ev*wr.y; l2 += ev*wr.z; l3 += ev*wr.w;
    }
    l0 += __shfl_xor(l0,1); l1 += __shfl_xor(l1,1);
    l2 += __shfl_xor(l2,1); l3 += __shfl_xor(l3,1);
    if ((lane & 1) == 0){
      float e0 = __expf(l0 > 0.f ? l0 : 2.f*(__expf(l0*0.5f)-1.f));
      float e1 = __expf(l1 > 0.f ? l1 : 2.f*(__expf(l1*0.5f)-1.f));
      float e2 = __expf(l2 > 0.f ? l2 : 2.f*(__expf(l2*0.5f)-1.f));
      float e3 = __expf(l3 > 0.f ? l3 : 2.f*(__expf(l3*0.5f)-1.f));
      *(float4*)(e4_out + (size_t)p*4) = make_float4(e0, e1, e2, e3);
    }
    uint4 o1 = make_uint4(pack2(ecache[0],ecache[1]),  pack2(ecache[2],ecache[3]),
                          pack2(ecache[4],ecache[5]),  pack2(ecache[6],ecache[7]));
    uint4 o2 = make_uint4(pack2(ecache[8],ecache[9]),  pack2(ecache[10],ecache[11]),
                          pack2(ecache[12],ecache[13]),pack2(ecache[14],ecache[15]));
    unsigned int* ep = edge_out + (size_t)p*16 + (lane&1)*8;
    *(uint4*)(ep)     = o1;
    *(uint4*)(ep + 4) = o2;
  }
}

// ---------------- aggregation v3: batched e4/dir4 staging (r9, kept) ----------
__global__ __launch_bounds__(256, 4) void k_agg(
    const int* __restrict__ offsets,
    const unsigned int* __restrict__ edgeb,
    const float* __restrict__ e4,
    const float* __restrict__ dir4,
    const unsigned short* __restrict__ wb4,
    const float* __restrict__ Wvm,
    unsigned int* __restrict__ semB, unsigned int* __restrict__ n2B,
    float* __restrict__ wsDv)
{
  __shared__ __align__(16) unsigned char sAllB[4*5632];
  const int wv   = threadIdx.x >> 6;
  const int lane = threadIdx.x & 63;
  unsigned char* sA = sAllB + wv*5632;        // 1 KB edge feats
  unsigned char* gC = sA + 1024;              // 4 KB transpose buffer
  float* sE = (float*)(sA + 5120);            // 16 x float4 e4
  float* sD = (float*)(sA + 5376);            // 16 x float4 dir4

  const int c    = lane & 31;
  const int l15  = lane & 15;
  const int quad = lane >> 4;
  const int half = lane >> 5;
  const bool low = (lane < 32);

  short8 b4[8];
  #pragma unroll
  for (int nf=0; nf<8; nf++)
    b4[nf] = ld_frag((const unsigned char*)wb4 + (size_t)(nf*64 + lane)*16);
  const float wvm_c = Wvm[c];

  const int i = blockIdx.x*4 + wv;
  if (i >= N_) return;
  const int n0 = offsets[i], n1 = offsets[i+1];
  const int cnt = n1 - n0;

  {
    const int nc0 = min(16, cnt);
    if (lane < 32){
      if (lane*32 < nc0*64){
        const uint4* src = (const uint4*)(edgeb + (size_t)n0*16 + lane*8);
        *(uint4*)(sA + lane*32)      = src[0];
        *(uint4*)(sA + lane*32 + 16) = src[1];
      }
    } else if (lane < 48){
      int k = lane - 32;
      if (k < nc0) *(float4*)(sE + k*4) = *(const float4*)(e4 + (size_t)(n0+k)*4);
    } else {
      int k = lane - 48;
      if (k < nc0) *(float4*)(sD + k*4) = *(const float4*)(dir4 + (size_t)(n0+k)*4);
    }
  }

  float d0=0.f,d1=0.f,d2=0.f,d3=0.f;
  for (int s = n0 + lane; s < n1; s += 64){
    const float4 ev = *(const float4*)(e4 + (size_t)s*4);
    d0+=ev.x; d1+=ev.y; d2+=ev.z; d3+=ev.w;
  }
  #pragma unroll
  for (int off=32; off>=1; off>>=1){
    d0 += __shfl_xor(d0,off); d1 += __shfl_xor(d1,off);
    d2 += __shfl_xor(d2,off); d3 += __shfl_xor(d3,off);
  }
  const float i0 = (cnt>0)?frcp(d0):0.f, i1 = (cnt>0)?frcp(d1):0.f;
  const float i2 = (cnt>0)?frcp(d2):0.f, i3 = (cnt>0)?frcp(d3):0.f;

  float sem4[4] = {0.f,0.f,0.f,0.f};
  float cx=0.f,cy=0.f,cz=0.f, gx=0.f,gy=0.f,gz=0.f;

  bool staged = true;                    // first chunk already staged
  for (int base = n0; base < n1; base += 16){
    const int nc = min(16, n1 - base);
    if (!staged){
      if (lane < 32){
        if (lane*32 < nc*64){
          const uint4* src = (const uint4*)(edgeb + (size_t)base*16 + lane*8);
          *(uint4*)(sA + lane*32)      = src[0];
          *(uint4*)(sA + lane*32 + 16) = src[1];
        }
      } else if (lane < 48){
        int k = lane - 32;
        if (k < nc) *(float4*)(sE + k*4) = *(const float4*)(e4 + (size_t)(base+k)*4);
      } else {
        int k = lane - 48;
        if (k < nc) *(float4*)(sD + k*4) = *(const float4*)(dir4 + (size_t)(base+k)*4);
      }
    }
    staged = false;
    {
      short8 a0 = ld_frag(sA + l15*64 + quad*16);
      f32x4 accg[8];
      #pragma unroll
      for (int nf=0; nf<8; nf++){
        f32x4 z = (f32x4){0.f,0.f,0.f,0.f};
        accg[nf] = mfma16(a0, b4[nf], z);
      }
      #pragma unroll
      for (int reg=0; reg<4; reg++){
        int row = quad*4 + reg;
        uint4 o = make_uint4(pack2(accg[0][reg],accg[1][reg]),
                             pack2(accg[2][reg],accg[3][reg]),
                             pack2(accg[4][reg],accg[5][reg]),
                             pack2(accg[6][reg],accg[7][reg]));
        *(uint4*)(gC + row*256 + l15*16) = o;
      }
    }
    for (int t0 = 0; t0 < nc; t0 += 2){
      const int rloc = t0 + half;
      const bool act = rloc < nc;
      const int rc = act ? rloc : 0;
      const float4 ev = *(const float4*)(sE + rc*4);
      const float4 dv = *(const float4*)(sD + rc*4);
      const float aw0 = ev.x*i0, aw1 = ev.y*i1, aw2 = ev.z*i2, aw3 = ev.w*i3;
      uint2 gv = *(const uint2*)(gC + rc*256 + c*8);
      float g0=u2f(gv.x<<16), g1=u2f(gv.x&0xffff0000u);
      float g2=u2f(gv.y<<16), g3=u2f(gv.y&0xffff0000u);
      float tp = aw0*g0 + aw1*g1 + aw2*g2 + aw3*g3;
      float tt = fminf(fmaxf(tp, -15.f), 15.f);
      float ex = __expf(2.f*tt);
      float th = (ex-1.f)*frcp(ex+1.f);
      unsigned int ew = *(const unsigned int*)(sA + rc*64 + (c>>1)*4);
      float ec = (c & 1) ? u2f(ew & 0xffff0000u) : u2f(ew << 16);
      if (act){
        sem4[0] += ec*aw0; sem4[1] += ec*aw1;
        sem4[2] += ec*aw2; sem4[3] += ec*aw3;
        cx += th*dv.x; cy += th*dv.y; cz += th*dv.z;
        float tw = th*wvm_c;
        gx += tw*dv.x; gy += tw*dv.y; gz += tw*dv.z;
      }
    }
  }

  #pragma unroll
  for (int j=0;j<4;j++) sem4[j] += __shfl_xor(sem4[j], 32);
  cx += __shfl_xor(cx,32); cy += __shfl_xor(cy,32); cz += __shfl_xor(cz,32);
  #pragma unroll
  for (int off=32; off>=1; off>>=1){
    gx += __shfl_xor(gx,off); gy += __shfl_xor(gy,off); gz += __shfl_xor(gz,off);
  }
  const float invc = frcp((float)(cnt > 1 ? cnt : 1));
  if (low){
    float mx = cx*invc, my = cy*invc, mz = cz*invc;
    float n2v = mx*mx + my*my + mz*mz;
    float n2o = __shfl_xor(n2v, 1);
    if ((c & 1) == 0) n2B[(size_t)i*16 + (c>>1)] = pack2(n2v, n2o);
    *(uint2*)(semB + (size_t)i*64 + c*2) =
        make_uint2(pack2(sem4[0],sem4[1]), pack2(sem4[2],sem4[3]));
  }
  if (lane == 0)
    *(float4*)(wsDv + (size_t)i*4) = make_float4(gx*invc, gy*invc, gz*invc, 0.f);
}

// ---------------- node MLP v5 (r14): 4-way column split, 4 waves / 16 rows ----------
// r13's 2-way split gained 11.2us; apply the proven lever once more. Wave w
// owns nf=w (output cols 16w..16w+15) of every stage. Per-wave chain ~15 MFMA
// + ~15 B-loads (was ~30); waves double to 6252 (~6/SIMD). Barriers: 5.
__global__ __launch_bounds__(256) void k_mlp(
    const float* __restrict__ h, const float* __restrict__ x, const float* __restrict__ v,
    const unsigned short* __restrict__ hb,
    const unsigned short* __restrict__ semB, const unsigned short* __restrict__ n2B,
    const float* __restrict__ wsDv,
    const unsigned short* __restrict__ wb5, const unsigned short* __restrict__ wb6,
    const unsigned short* __restrict__ wb7, const unsigned short* __restrict__ wb8,
    const unsigned short* __restrict__ wb9,
    const float* __restrict__ bpn1, const float* __restrict__ bpn2,
    const float* __restrict__ bn1,  const float* __restrict__ bn2,
    const float* __restrict__ bv1,  const float* __restrict__ Wv2,
    float* __restrict__ out)
{
  __shared__ __align__(16) unsigned char sT[16*136];   // intermediate A (S1 out, N1 out)
  __shared__ __align__(16) unsigned char sU[16*136];   // intermediate B (S2 out, hnew)
  __shared__ float sPart[4*16];                        // V1 cross-wave combine

  const int tid  = threadIdx.x;
  const int wv   = tid >> 6;          // 0..3: owns nf = wv
  const int lane = tid & 63;
  const int l15  = lane & 15;
  const int quad = lane >> 4;
  const int base = blockIdx.x*16;
  const int r0a  = min(base + l15, N_-1);
  const unsigned char* hB  = (const unsigned char*)hb;
  const unsigned char* sB  = (const unsigned char*)semB;
  const unsigned char* nB  = (const unsigned char*)n2B;
  const int ncol = 16*wv + l15;       // this wave's output column

  // ---- S1: n2 [16 x 32] @ wb5 -> silu -> sT (cols 16wv..16wv+15) ----
  {
    float b = bpn1[ncol];
    f32x4 acc = (f32x4){b,b,b,b};
    short8 a0 = ld_frag(nB + (size_t)r0a*64 + quad*16);
    short8 bb = ld_frag((const unsigned char*)wb5 + (size_t)(wv*64 + lane)*16);
    acc = mfma16(a0, bb, acc);
    #pragma unroll
    for (int reg=0; reg<4; reg++){
      int row = quad*4 + reg;
      ((unsigned short*)(sT + row*136))[ncol] = (unsigned short)f2b16(silu_f(acc[reg]));
    }
  }
  __syncthreads();
  // ---- S2: sT [16 x 64] @ wb6 -> silu -> sU ----
  {
    float b = bpn2[ncol];
    f32x4 acc = (f32x4){b,b,b,b};
    #pragma unroll
    for (int s=0; s<2; s++){
      int koff = s*32 + quad*8;
      short8 a0 = ld_frag(sT + l15*136 + koff*2);
      short8 bb = ld_frag((const unsigned char*)wb6 + (size_t)((wv*2 + s)*64 + lane)*16);
      acc = mfma16(a0, bb, acc);
    }
    #pragma unroll
    for (int reg=0; reg<4; reg++){
      int row = quad*4 + reg;
      ((unsigned short*)(sU + row*136))[ncol] = (unsigned short)f2b16(silu_f(acc[reg]));
    }
  }
  __syncthreads();
  // ---- N1 (K=256): [h | sem | sp] @ wb7 -> silu -> sT ----
  {
    float b = bn1[ncol];
    f32x4 acc = (f32x4){b,b,b,b};
    #pragma unroll
    for (int s=0; s<8; s++){
      int koff = s*32 + quad*8;
      short8 a0;
      if (koff < 64){
        a0 = ld_frag(hB + (size_t)r0a*128 + koff*2);
      } else if (koff < 192){
        a0 = ld_frag(sB + (size_t)r0a*256 + (koff-64)*2);
      } else {
        a0 = ld_frag(sU + l15*136 + (koff-192)*2);
      }
      short8 bb = ld_frag((const unsigned char*)wb7 + (size_t)((wv*8 + s)*64 + lane)*16);
      acc = mfma16(a0, bb, acc);
    }
    #pragma unroll
    for (int reg=0; reg<4; reg++){
      int row = quad*4 + reg;
      ((unsigned short*)(sT + row*136))[ncol] = (unsigned short)f2b16(silu_f(acc[reg]));
    }
  }
  __syncthreads();
  // ---- N2 + residual: sT @ wb8 -> out (own cols), hnew -> sU ----
  {
    float b = bn2[ncol];
    f32x4 acc = (f32x4){b,b,b,b};
    #pragma unroll
    for (int s=0; s<2; s++){
      int koff = s*32 + quad*8;
      short8 a0 = ld_frag(sT + l15*136 + koff*2);
      short8 bb = ld_frag((const unsigned char*)wb8 + (size_t)((wv*2 + s)*64 + lane)*16);
      acc = mfma16(a0, bb, acc);
    }
    #pragma unroll
    for (int reg=0; reg<4; reg++){
      int row = quad*4 + reg;
      int node = base + row;
      float hv = (node < N_) ? h[(size_t)node*64 + ncol] : 0.f;
      float hnew = hv + silu_f(acc[reg]);
      if (node < N_) out[(size_t)node*64 + ncol] = hnew;
      ((unsigned short*)(sU + row*136))[ncol] = (unsigned short)f2b16(hnew);
    }
  }
  __syncthreads();
  // ---- V1 + gate + v/x ----
  {
    float b = bv1[ncol];
    f32x4 acc = (f32x4){b,b,b,b};
    #pragma unroll
    for (int s=0; s<2; s++){
      int koff = s*32 + quad*8;
      short8 a0 = ld_frag(sU + l15*136 + koff*2);
      short8 bb = ld_frag((const unsigned char*)wb9 + (size_t)((wv*2 + s)*64 + lane)*16);
      acc = mfma16(a0, bb, acc);
    }
    float part[4];
    float w2 = Wv2[ncol];
    #pragma unroll
    for (int reg=0; reg<4; reg++) part[reg] = silu_f(acc[reg]) * w2;
    #pragma unroll
    for (int reg=0; reg<4; reg++){
      #pragma unroll
      for (int off=1; off<16; off<<=1)
        part[reg] += __shfl_xor(part[reg], off);
    }
    if (l15 == 0){
      #pragma unroll
      for (int reg=0; reg<4; reg++)
        sPart[wv*16 + quad*4 + reg] = part[reg];
    }
    __syncthreads();
    if (wv == 0 && l15 == 0){
      #pragma unroll
      for (int reg=0; reg<4; reg++){
        int row = quad*4 + reg;
        int node = base + row;
        if (node < N_){
          float p = sPart[row] + sPart[16 + row] + sPart[32 + row] + sPart[48 + row];
          float gate = 2.f*frcp(1.f + __expf(-p));
          float4 dvv = *(const float4*)(wsDv + (size_t)node*4);
          float dvs[3] = {dvv.x, dvv.y, dvv.z};
          #pragma unroll
          for (int ax=0; ax<3; ax++){
            float vn = gate * v[(size_t)node*3 + ax] + dvs[ax];
            out[(size_t)N_*64 + (size_t)node*3 + ax]                 = x[(size_t)node*3 + ax] + vn;
            out[(size_t)N_*64 + (size_t)N_*3 + (size_t)node*3 + ax]  = vn;
          }
        }
      }
    }
  }
}

// ---------------- launch ----------------
extern "C" void kernel_launch(void* const* d_in, const int* in_sizes, int n_in,
                              void* d_out, int out_size, void* d_ws, size_t ws_size,
                              hipStream_t stream)
{
  const float* h = (const float*)d_in[0];
  const float* x = (const float*)d_in[1];
  const float* v = (const float*)d_in[2];
  const int* idx_i = (const int*)d_in[3];
  const int* idx_j = (const int*)d_in[4];
  const float* Wein = (const float*)d_in[5];  const float* bein = (const float*)d_in[6];
  const float* Weo1 = (const float*)d_in[7];  const float* beo1 = (const float*)d_in[8];
  const float* Weo2 = (const float*)d_in[9];  const float* beo2 = (const float*)d_in[10];
  const float* Watt = (const float*)d_in[11]; const float* batt = (const float*)d_in[12];
  const float* Wxm  = (const float*)d_in[13]; const float* Wvm  = (const float*)d_in[14];
  const float* Wpn1 = (const float*)d_in[15]; const float* bpn1 = (const float*)d_in[16];
  const float* Wpn2 = (const float*)d_in[17]; const float* bpn2 = (const float*)d_in[18];
  const float* Wn1  = (const float*)d_in[19]; const float* bn1  = (const float*)d_in[20];
  const float* Wn2  = (const float*)d_in[21]; const float* bn2  = (const float*)d_in[22];
  const float* Wv1  = (const float*)d_in[23]; const float* bv1  = (const float*)d_in[24];
  const float* Wv2  = (const float*)d_in[25];

  float* wsf        = (float*)d_ws;
  int*   cnt        = (int*)(wsf + OFF_CNT);
  int*   offsets    = (int*)(wsf + OFF_OFFSETS);
  unsigned int* edgeb = (unsigned int*)(wsf + OFF_EDGE);
  float* e4o        = wsf + OFF_E4;
  float* diro       = wsf + OFF_DIR;
  unsigned int* semB = (unsigned int*)(wsf + OFF_SEM);
  unsigned int* n2B  = (unsigned int*)(wsf + OFF_N2);
  float* wsDv       = wsf + OFF_DV;
  unsigned short* wb1 = (unsigned short*)(wsf + OFF_WB1);
  unsigned short* wb2 = (unsigned short*)(wsf + OFF_WB2);
  unsigned short* wb3 = (unsigned short*)(wsf + OFF_WB3);
  unsigned short* wb4 = (unsigned short*)(wsf + OFF_WB4);
  unsigned short* wb5 = (unsigned short*)(wsf + OFF_WB5);
  unsigned short* wb6 = (unsigned short*)(wsf + OFF_WB6);
  unsigned short* wb7 = (unsigned short*)(wsf + OFF_WB7);
  unsigned short* wb8 = (unsigned short*)(wsf + OFF_WB8);
  unsigned short* wb9 = (unsigned short*)(wsf + OFF_WB9);
  unsigned int*   hb  = (unsigned int*)(wsf + OFF_HB);
  int*            sij = (int*)(wsf + OFF_SIJ);
  int*            rnk = (int*)(wsf + OFF_RANK);

  hipMemsetAsync(cnt, 0, N_*sizeof(int), stream);
  k_hist<<<(P_+255)/256, 256, 0, stream>>>(idx_i, cnt, rnk);
  k_scan2<<<65, 1024, 0, stream>>>(cnt, offsets, h,
                                   Wein, Weo1, Weo2, Wxm, Wpn1, Wpn2,
                                   Wn1, Wn2, Wv1,
                                   hb, wb1, wb2, wb3, wb4,
                                   wb5, wb6, wb7, wb8, wb9);
  k_scatter3<<<(P_+255)/256, 256, 0, stream>>>(idx_i, idx_j, offsets, rnk, sij);
  k_edge2<<<P_/128, 256, 0, stream>>>((const unsigned short*)hb, sij, x, diro,
                                      wb1, wb2, wb3,
                                      bein, beo1, beo2, Watt, batt,
                                      edgeb, e4o);
  k_agg<<<(N_+3)/4, 256, 0, stream>>>(offsets, edgeb, e4o, diro, wb4, Wvm,
                                      semB, n2B, wsDv);
  k_mlp<<<(N_+15)/16, 256, 0, stream>>>(h, x, v,
                                        (const unsigned short*)hb,
                                        (const unsigned short*)semB,
                                        (const unsigned short*)n2B,
                                        wsDv,
                                        wb5, wb6, wb7, wb8, wb9,
                                        bpn1, bpn2, bn1, bn2, bv1, Wv2,
                                        (float*)d_out);
}

// Round 16
// 256.853 us; speedup vs baseline: 1.0239x; 1.0239x over previous
//
#include <hip/hip_runtime.h>
#include <hip/hip_bf16.h>

#define DEV __device__ __forceinline__

constexpr int N_ = 25000;
constexpr int P_ = 400000;

// ---------------- ws layout (units of 4 bytes) ----------------
constexpr int align4(int xx){ return (xx+3)&~3; }
constexpr int OFF_CNT     = 0;                          // N ints
constexpr int OFF_OFFSETS = align4(OFF_CNT + N_);       // N+1 ints
constexpr int OFF_CURSOR  = align4(OFF_OFFSETS + N_ + 1); // (unused since r11)
constexpr int OFF_EDGE    = align4(OFF_CURSOR + N_);    // P*16 dwords (32 bf16 edge feats, sorted order)
constexpr int OFF_E4      = OFF_EDGE + P_*16;           // P*4  f32
constexpr int OFF_DIR     = OFF_E4 + P_*4;              // P*4  f32 (written by k_edge2, coalesced)
constexpr int OFF_SEM     = align4(OFF_DIR + P_*4);     // N*64 dw  (bf16 sem, 128 cols)
constexpr int OFF_N2      = OFF_SEM + N_*64;            // N*16 dw  (bf16 n2, 32 cols)
constexpr int OFF_DV      = OFF_N2 + N_*16;             // N*4 f32
constexpr int OFF_WB5     = OFF_DV + N_*4;              // 1024 dw (frag order)
constexpr int OFF_WB6     = OFF_WB5 + 1024;             // 2048 dw
constexpr int OFF_WB7     = OFF_WB6 + 2048;             // 8192 dw
constexpr int OFF_WB8     = OFF_WB7 + 8192;             // 2048 dw
constexpr int OFF_WB9     = OFF_WB8 + 2048;             // 2048 dw
constexpr int OFF_HB      = OFF_WB9 + 2048;             // h as bf16: N*32 dw
constexpr int OFF_SIJ     = OFF_HB + N_*32;             // sorted (i,j) pairs: P*2 ints
constexpr int OFF_WB1     = OFF_SIJ + P_*2;             // 8192 dw (frag order)
constexpr int OFF_WB2     = OFF_WB1 + 8192;             // 2048 dw
constexpr int OFF_WB3     = OFF_WB2 + 2048;             // 1024 dw
constexpr int OFF_WB4     = OFF_WB3 + 1024;             // 2048 dw (frag order + logical col permute)
constexpr int OFF_RANK    = OFF_WB4 + 2048;             // P ints: edge rank within node (r11)
constexpr int WS_UNITS    = OFF_RANK + P_;

// PhysNet RBF constants (K=50, r_max=0.5)
constexpr float MU0F  = 0.60653065971263342f;               // exp(-0.5)
constexpr float DMUF  = (1.0f - 0.60653065971263342f) / 49.0f;
constexpr float BETAF = 1.0f / ((0.04f * (1.0f - 0.60653065971263342f)) *
                                (0.04f * (1.0f - 0.60653065971263342f)));
constexpr float EPSF  = 1e-8f;

DEV float u2f(unsigned int u){ union{unsigned int i; float f;} c; c.i=u; return c.f; }
DEV unsigned int f2b16(float f){
  __hip_bfloat16 b = __float2bfloat16(f);
  unsigned short s; __builtin_memcpy(&s, &b, 2);
  return (unsigned int)s;
}
DEV unsigned int pack2(float a, float b){ return f2b16(a) | (f2b16(b) << 16); }
// v_rcp_f32 (~1 ulp) instead of IEEE div; negligible vs bf16 rounding.
DEV float frcp(float x){ return __builtin_amdgcn_rcpf(x); }
DEV float silu_f(float v){ return v * frcp(1.0f + __expf(-v)); }

using short8 = __attribute__((ext_vector_type(8))) short;   // 8 bf16 (4 VGPRs)
using f32x4  = __attribute__((ext_vector_type(4))) float;
union U4S8 { uint4 u; short8 s; };
DEV short8 ld_frag(const void* p){ U4S8 c; c.u = *(const uint4*)p; return c.s; }
DEV f32x4 mfma16(short8 a, short8 b, f32x4 c){
  return __builtin_amdgcn_mfma_f32_16x16x32_bf16(a, b, c, 0, 0, 0);
}

// ---------------- hist (r11): histogram + RANK CAPTURE ----------------
__global__ void k_hist(const int* __restrict__ idx_i,
                       int* __restrict__ cnt, int* __restrict__ rank){
  int t = blockIdx.x*256 + threadIdx.x;
  if (t < P_) rank[t] = atomicAdd(&cnt[idx_i[t]], 1);
}

// ---------------- scan v3 (r11): block 0 scans; blocks 1..N transpose --------------
__global__ __launch_bounds__(1024) void k_scan2(
    const int* __restrict__ cnt, int* __restrict__ offsets,
    const float* __restrict__ h,
    const float* __restrict__ Wein, const float* __restrict__ Weo1,
    const float* __restrict__ Weo2, const float* __restrict__ Wxm,
    const float* __restrict__ Wpn1, const float* __restrict__ Wpn2,
    const float* __restrict__ Wn1,  const float* __restrict__ Wn2,
    const float* __restrict__ Wv1,
    unsigned int* __restrict__ hb,
    unsigned short* __restrict__ wb1, unsigned short* __restrict__ wb2,
    unsigned short* __restrict__ wb3, unsigned short* __restrict__ wb4,
    unsigned short* __restrict__ wb5, unsigned short* __restrict__ wb6,
    unsigned short* __restrict__ wb7, unsigned short* __restrict__ wb8,
    unsigned short* __restrict__ wb9){
  __shared__ unsigned short sCnt[N_];   // 50 KB (block 0 only touches it)
  __shared__ int swv[16];
  if (blockIdx.x == 0){
    const int t = threadIdx.x;
    const int wv = t >> 6, ln = t & 63;
    for (int q = t; q < N_; q += 1024) sCnt[q] = (unsigned short)cnt[q];
    __syncthreads();
    constexpr int CH = (N_ + 1023)/1024;   // 25
    int b = t*CH, e = b+CH;
    if (b > N_) b = N_;
    if (e > N_) e = N_;
    int s = 0;
    for (int q=b; q<e; q++) s += sCnt[q];
    int incl = s;
    #pragma unroll
    for (int off=1; off<64; off<<=1){
      int vv = __shfl_up(incl, off);
      if (ln >= off) incl += vv;
    }
    if (ln == 63) swv[wv] = incl;
    __syncthreads();
    if (wv == 0 && ln < 16){
      int w = swv[ln];
      #pragma unroll
      for (int off=1; off<16; off<<=1){
        int vv = __shfl_up(w, off);
        if (ln >= off) w += vv;
      }
      swv[ln] = w;
    }
    __syncthreads();
    const int wpre = (wv > 0) ? swv[wv-1] : 0;
    int run = wpre + incl - s;
    for (int q=b; q<e; q++){ offsets[q] = run; run += sCnt[q]; }
    if (t == 1023) offsets[N_] = run;
    return;
  }
  // ---- blocks 1..gridDim-1: hb conversion + frag-ordered weight transposes ----
  int t = (blockIdx.x-1)*1024 + threadIdx.x;
  const int st = (gridDim.x-1)*1024;
  for (int q=t; q<N_*32; q+=st){
    float2 a = *(const float2*)(h + (size_t)q*2);
    hb[q] = pack2(a.x, a.y);
  }
  // wb1: nf 0..7 (n=16nf+l15 over 0..127), s 0..3 (K=128)
  for (int q=t; q<8*4*64*8; q+=st){
    int e=q&7, lane=(q>>3)&63, sx=(q>>9)&3, nf=q>>11;
    int l15=lane&15, quad=lane>>4;
    int n = 16*nf + l15, k = sx*32 + quad*8 + e;
    float v = (n<50) ? Wein[k*50+n] : ((n<64) ? 0.f : Weo1[k*64+(n-64)]);
    wb1[q] = (unsigned short)f2b16(v);
  }
  // wb2: nf 0..3, s 0..1 (K=64); k<50 -> Weo1[128+k], k==50 -> Weo1[178], else 0
  for (int q=t; q<4*2*64*8; q+=st){
    int e=q&7, lane=(q>>3)&63, sx=(q>>9)&1, nf=q>>10;
    int l15=lane&15, quad=lane>>4;
    int n = 16*nf + l15, k = sx*32 + quad*8 + e;
    float v = (k<50) ? Weo1[(128+k)*64+n] : ((k==50) ? Weo1[178*64+n] : 0.f);
    wb2[q] = (unsigned short)f2b16(v);
  }
  // wb3: nf 0..1, s 0..1
  for (int q=t; q<2*2*64*8; q+=st){
    int e=q&7, lane=(q>>3)&63, sx=(q>>9)&1, nf=q>>10;
    int l15=lane&15, quad=lane>>4;
    int n = 16*nf + l15, k = sx*32 + quad*8 + e;
    wb3[q] = (unsigned short)f2b16(Weo2[k*32+n]);
  }
  // wb4: nf 0..7, K=32; physical n=16nf+l15 holds logical n_log=l15*8+nf
  for (int q=t; q<8*64*8; q+=st){
    int e=q&7, lane=(q>>3)&63, nf=q>>9;
    int l15=lane&15, quad=lane>>4;
    int k = quad*8 + e;
    int n_log = l15*8 + nf;
    int cc = n_log>>2, hh = n_log&3;
    wb4[q] = (unsigned short)f2b16(Wxm[(k*4+hh)*32 + cc]);
  }
  // wb5: nf 0..3, K=32
  for (int q=t; q<4*64*8; q+=st){
    int e=q&7, lane=(q>>3)&63, nf=q>>9;
    int l15=lane&15, quad=lane>>4;
    int n = 16*nf + l15, k = quad*8 + e;
    wb5[q] = (unsigned short)f2b16(Wpn1[k*64+n]);
  }
  // wb6 / wb8 / wb9: nf 0..3, s 0..1 (64x64 mats)
  for (int q=t; q<4*2*64*8; q+=st){
    int e=q&7, lane=(q>>3)&63, sx=(q>>9)&1, nf=q>>10;
    int l15=lane&15, quad=lane>>4;
    int n = 16*nf + l15, k = sx*32 + quad*8 + e;
    wb6[q] = (unsigned short)f2b16(Wpn2[k*64+n]);
    wb8[q] = (unsigned short)f2b16(Wn2[k*64+n]);
    wb9[q] = (unsigned short)f2b16(Wv1[k*64+n]);
  }
  // wb7: nf 0..3, s 0..7 (K=256)
  for (int q=t; q<4*8*64*8; q+=st){
    int e=q&7, lane=(q>>3)&63, sx=(q>>9)&7, nf=q>>12;
    int l15=lane&15, quad=lane>>4;
    int n = 16*nf + l15, k = sx*32 + quad*8 + e;
    wb7[q] = (unsigned short)f2b16(Wn1[k*64+n]);
  }
}

// ---------------- scatter v4 (r11): ATOMIC-FREE ----------------
__global__ void k_scatter3(const int* __restrict__ idx_i, const int* __restrict__ idx_j,
                           const int* __restrict__ offsets, const int* __restrict__ rank,
                           int* __restrict__ sij){
  int t = blockIdx.x*256 + threadIdx.x;
  if (t >= P_) return;
  int i = idx_i[t], j = idx_j[t];
  int pos = offsets[i] + rank[t];
  *(int2*)(sij + (size_t)pos*2) = make_int2(i, j);
}

// ---------------- MFMA edge kernel (r11 proven: ~54 us) ----------------
// r12 lesson: widening to 64 edges/wave made the allocator clamp at 88 VGPR
// (live set >=128) and reload A-frags between phases -> 73.7us. This 32-edge
// interleaved form is the structure's local optimum. Do not widen.
__global__ __launch_bounds__(256, 4) void k_edge2(
    const unsigned short* __restrict__ hb,
    const int* __restrict__ sij, const float* __restrict__ x,
    float* __restrict__ dir4,
    const unsigned short* __restrict__ wb1, const unsigned short* __restrict__ wb2,
    const unsigned short* __restrict__ wb3,
    const float* __restrict__ bein, const float* __restrict__ beo1,
    const float* __restrict__ beo2, const float* __restrict__ Watt,
    const float* __restrict__ batt,
    unsigned int* __restrict__ edge_out, float* __restrict__ e4_out)
{
  __shared__ __align__(16) unsigned char sAll[4*4608];   // 18432 B (1 scratch/wave)
  __shared__ float sdv[128];
  __shared__ float semd[128];

  const int tid  = threadIdx.x;
  const int wv   = tid >> 6;
  const int lane = tid & 63;
  const int l15  = lane & 15;
  const int quad = lane >> 4;
  const int pbase = blockIdx.x * 128;
  unsigned char* sW = sAll + wv*4608;

  // ---- geometry: sij coalesced read, x gathers (L2-hit), dir4 coalesced write ----
  if (lane < 32){
    int row = 32*wv + lane;
    int2 ij = *(const int2*)(sij + (size_t)(pbase + row)*2);
    float xi0=x[ij.x*3], xi1=x[ij.x*3+1], xi2=x[ij.x*3+2];
    float xj0=x[ij.y*3], xj1=x[ij.y*3+1], xj2=x[ij.y*3+2];
    float rx=xj0-xi0, ry=xj1-xi1, rz=xj2-xi2;
    float d = sqrtf(rx*rx+ry*ry+rz*rz+EPSF);
    float iv = frcp(d+EPSF);
    sdv[row]  = d;
    semd[row] = __expf(-d);
    *(float4*)(dir4 + (size_t)(pbase + row)*4) = make_float4(rx*iv, ry*iv, rz*iv, d);
  }

  // ---- A-fragments straight from global hb (row = 128 B of bf16) ----
  short8 af0[4], af1[4];
  {
    const int rbase = pbase + 32*wv;
    int2 ij0 = *(const int2*)(sij + (size_t)(rbase + l15)*2);
    int2 ij1 = *(const int2*)(sij + (size_t)(rbase + 16 + l15)*2);
    const unsigned char* hB = (const unsigned char*)hb;
    af0[0] = ld_frag(hB + (size_t)ij0.x*128 + quad*16);
    af0[1] = ld_frag(hB + (size_t)ij0.x*128 + 64 + quad*16);
    af0[2] = ld_frag(hB + (size_t)ij0.y*128 + quad*16);
    af0[3] = ld_frag(hB + (size_t)ij0.y*128 + 64 + quad*16);
    af1[0] = ld_frag(hB + (size_t)ij1.x*128 + quad*16);
    af1[1] = ld_frag(hB + (size_t)ij1.x*128 + 64 + quad*16);
    af1[2] = ld_frag(hB + (size_t)ij1.y*128 + quad*16);
    af1[3] = ld_frag(hB + (size_t)ij1.y*128 + 64 + quad*16);
  }

  // ---- GEMM-1a: [32 x 128] @ WB1[nf 0..3] (Wein) ----
  f32x4 acc[2][4];
  #pragma unroll
  for (int mf=0; mf<2; mf++)
    #pragma unroll
    for (int nf=0; nf<4; nf++){
      int nn = 16*nf + l15;
      float bias = (nn < 50) ? bein[nn] : 0.f;
      acc[mf][nf] = (f32x4){bias, bias, bias, bias};
    }
  #pragma unroll
  for (int s=0; s<4; s++){
    #pragma unroll
    for (int nf=0; nf<4; nf++){
      short8 b = ld_frag((const unsigned char*)wb1 + (size_t)((nf*4 + s)*64 + lane)*16);
      acc[0][nf] = mfma16(af0[s], b, acc[0][nf]);
      acc[1][nf] = mfma16(af1[s], b, acc[1][nf]);
    }
  }

  // ---- epilogue 1: RBF -> A2 bf16 [lrow][72 ushort] at sW ----
  #pragma unroll
  for (int mf=0; mf<2; mf++)
    #pragma unroll
    for (int nf=0; nf<4; nf++){
      int n = 16*nf + l15;
      float mu = MU0F + (float)n*DMUF;
      #pragma unroll
      for (int reg=0; reg<4; reg++){
        int lrow = 16*mf + quad*4 + reg;
        int grow = 32*wv + lrow;
        float t = semd[grow] - mu;
        float fv = acc[mf][nf][reg] * __expf(-BETAF*t*t);
        unsigned short ob;
        if (n < 50)       ob = (unsigned short)f2b16(fv);
        else if (n == 50) ob = (unsigned short)f2b16(sdv[grow]);
        else              ob = 0;
        ((unsigned short*)sW)[lrow*72 + n] = ob;
      }
    }

  // ---- GEMM-1b: @ WB1[nf 4..7] (Weo1-top) into reused acc ----
  #pragma unroll
  for (int mf=0; mf<2; mf++)
    #pragma unroll
    for (int nf=0; nf<4; nf++){
      float bias = beo1[16*nf + l15];
      acc[mf][nf] = (f32x4){bias, bias, bias, bias};
    }
  #pragma unroll
  for (int s=0; s<4; s++){
    #pragma unroll
    for (int nf=0; nf<4; nf++){
      short8 b = ld_frag((const unsigned char*)wb1 + (size_t)(((4+nf)*4 + s)*64 + lane)*16);
      acc[0][nf] = mfma16(af0[s], b, acc[0][nf]);
      acc[1][nf] = mfma16(af1[s], b, acc[1][nf]);
    }
  }

  // ---- GEMM-2: += A2 [32 x 64] @ WB2 [64 x 64] ----
  #pragma unroll
  for (int s=0; s<2; s++){
    int koff = s*32 + quad*8;
    short8 a0 = ld_frag(sW + l15*144      + koff*2);
    short8 a1 = ld_frag(sW + (16+l15)*144 + koff*2);
    #pragma unroll
    for (int nf=0; nf<4; nf++){
      short8 b = ld_frag((const unsigned char*)wb2 + (size_t)((nf*2 + s)*64 + lane)*16);
      acc[0][nf] = mfma16(a0, b, acc[0][nf]);
      acc[1][nf] = mfma16(a1, b, acc[1][nf]);
    }
  }

  // ---- epilogue 2: silu -> A3 bf16, OVERWRITING the A2 scratch (in-order DS) ----
  unsigned char* A3 = sW;
  #pragma unroll
  for (int mf=0; mf<2; mf++)
    #pragma unroll
    for (int nf=0; nf<4; nf++){
      int n = 16*nf + l15;
      #pragma unroll
      for (int reg=0; reg<4; reg++){
        int lrow = 16*mf + quad*4 + reg;
        ((unsigned short*)A3)[lrow*72 + n] = (unsigned short)f2b16(silu_f(acc[mf][nf][reg]));
      }
    }

  // ---- GEMM-3: [32 x 64] @ WB3 [64 x 32] ----
  f32x4 acc3[2][2];
  #pragma unroll
  for (int mf=0; mf<2; mf++)
    #pragma unroll
    for (int nf=0; nf<2; nf++){
      float bias = beo2[16*nf + l15];
      acc3[mf][nf] = (f32x4){bias, bias, bias, bias};
    }
  #pragma unroll
  for (int s=0; s<2; s++){
    int koff = s*32 + quad*8;
    short8 a0 = ld_frag(A3 + l15*144      + koff*2);
    short8 a1 = ld_frag(A3 + (16+l15)*144 + koff*2);
    #pragma unroll
    for (int nf=0; nf<2; nf++){
      short8 b = ld_frag((const unsigned char*)wb3 + (size_t)((nf*2 + s)*64 + lane)*16);
      acc3[0][nf] = mfma16(a0, b, acc3[0][nf]);
      acc3[1][nf] = mfma16(a1, b, acc3[1][nf]);
    }
  }

  // ---- epilogue 3: C3 f32 [lrow][36 f32], again overwriting the scratch ----
  #pragma unroll
  for (int mf=0; mf<2; mf++)
    #pragma unroll
    for (int nf=0; nf<2; nf++){
      int n = 16*nf + l15;
      #pragma unroll
      for (int reg=0; reg<4; reg++){
        int lrow = 16*mf + quad*4 + reg;
        ((float*)sW)[lrow*36 + n] = acc3[mf][nf][reg];
      }
    }

  // ---- attention + stores (2 lanes per row) ----
  {
    int rr = lane >> 1;
    int p = pbase + 32*wv + rr;
    int cb = (lane & 1) * 16;
    const float* er = (const float*)(sW + rr*144);
    float l0, l1, l2, l3;
    if ((lane & 1) == 0){ l0 = batt[0]; l1 = batt[1]; l2 = batt[2]; l3 = batt[3]; }
    else                { l0 = l1 = l2 = l3 = 0.f; }
    float ecache[16];
    {
      float4 v0 = *(const float4*)(er + cb);
      float4 v1 = *(const float4*)(er + cb + 4);
      float4 v2 = *(const float4*)(er + cb + 8);
      float4 v3 = *(const float4*)(er + cb + 12);
      ecache[0]=v0.x; ecache[1]=v0.y; ecache[2]=v0.z; ecache[3]=v0.w;
      ecache[4]=v1.x; ecache[5]=v1.y; ecache[6]=v1.z; ecache[7]=v1.w;
      ecache[8]=v2.x; ecache[9]=v2.y; ecache[10]=v2.z; ecache[11]=v2.w;
      ecache[12]=v3.x; ecache[13]=v3.y; ecache[14]=v3.z; ecache[15]=v3.w;
    }
    #pragma unroll
    for (int c=0;c<16;c++){
      float ev = ecache[c];
      const float4 wr = *(const float4*)(Watt + (cb + c)*4);
      l0 += ev*wr.x; l1 += ev*wr.y; l2 += ev*wr.z; l3 += ev*wr.w;
    }
    l0 += __shfl_xor(l0,1); l1 += __shfl_xor(l1,1);
    l2 += __shfl_xor(l2,1); l3 += __shfl_xor(l3,1);
    if ((lane & 1) == 0){
      float e0 = __expf(l0 > 0.f ? l0 : 2.f*(__expf(l0*0.5f)-1.f));
      float e1 = __expf(l1 > 0.f ? l1 : 2.f*(__expf(l1*0.5f)-1.f));
      float e2 = __expf(l2 > 0.f ? l2 : 2.f*(__expf(l2*0.5f)-1.f));
      float e3 = __expf(l3 > 0.f ? l3 : 2.f*(__expf(l3*0.5f)-1.f));
      *(float4*)(e4_out + (size_t)p*4) = make_float4(e0, e1, e2, e3);
    }
    uint4 o1 = make_uint4(pack2(ecache[0],ecache[1]),  pack2(ecache[2],ecache[3]),
                          pack2(ecache[4],ecache[5]),  pack2(ecache[6],ecache[7]));
    uint4 o2 = make_uint4(pack2(ecache[8],ecache[9]),  pack2(ecache[10],ecache[11]),
                          pack2(ecache[12],ecache[13]),pack2(ecache[14],ecache[15]));
    unsigned int* ep = edge_out + (size_t)p*16 + (lane&1)*8;
    *(uint4*)(ep)     = o1;
    *(uint4*)(ep + 4) = o2;
  }
}

// ---------------- aggregation v3: batched e4/dir4 staging (r9, kept) ----------
__global__ __launch_bounds__(256, 4) void k_agg(
    const int* __restrict__ offsets,
    const unsigned int* __restrict__ edgeb,
    const float* __restrict__ e4,
    const float* __restrict__ dir4,
    const unsigned short* __restrict__ wb4,
    const float* __restrict__ Wvm,
    unsigned int* __restrict__ semB, unsigned int* __restrict__ n2B,
    float* __restrict__ wsDv)
{
  __shared__ __align__(16) unsigned char sAllB[4*5632];
  const int wv   = threadIdx.x >> 6;
  const int lane = threadIdx.x & 63;
  unsigned char* sA = sAllB + wv*5632;        // 1 KB edge feats
  unsigned char* gC = sA + 1024;              // 4 KB transpose buffer
  float* sE = (float*)(sA + 5120);            // 16 x float4 e4
  float* sD = (float*)(sA + 5376);            // 16 x float4 dir4

  const int c    = lane & 31;
  const int l15  = lane & 15;
  const int quad = lane >> 4;
  const int half = lane >> 5;
  const bool low = (lane < 32);

  short8 b4[8];
  #pragma unroll
  for (int nf=0; nf<8; nf++)
    b4[nf] = ld_frag((const unsigned char*)wb4 + (size_t)(nf*64 + lane)*16);
  const float wvm_c = Wvm[c];

  const int i = blockIdx.x*4 + wv;
  if (i >= N_) return;
  const int n0 = offsets[i], n1 = offsets[i+1];
  const int cnt = n1 - n0;

  {
    const int nc0 = min(16, cnt);
    if (lane < 32){
      if (lane*32 < nc0*64){
        const uint4* src = (const uint4*)(edgeb + (size_t)n0*16 + lane*8);
        *(uint4*)(sA + lane*32)      = src[0];
        *(uint4*)(sA + lane*32 + 16) = src[1];
      }
    } else if (lane < 48){
      int k = lane - 32;
      if (k < nc0) *(float4*)(sE + k*4) = *(const float4*)(e4 + (size_t)(n0+k)*4);
    } else {
      int k = lane - 48;
      if (k < nc0) *(float4*)(sD + k*4) = *(const float4*)(dir4 + (size_t)(n0+k)*4);
    }
  }

  float d0=0.f,d1=0.f,d2=0.f,d3=0.f;
  for (int s = n0 + lane; s < n1; s += 64){
    const float4 ev = *(const float4*)(e4 + (size_t)s*4);
    d0+=ev.x; d1+=ev.y; d2+=ev.z; d3+=ev.w;
  }
  #pragma unroll
  for (int off=32; off>=1; off>>=1){
    d0 += __shfl_xor(d0,off); d1 += __shfl_xor(d1,off);
    d2 += __shfl_xor(d2,off); d3 += __shfl_xor(d3,off);
  }
  const float i0 = (cnt>0)?frcp(d0):0.f, i1 = (cnt>0)?frcp(d1):0.f;
  const float i2 = (cnt>0)?frcp(d2):0.f, i3 = (cnt>0)?frcp(d3):0.f;

  float sem4[4] = {0.f,0.f,0.f,0.f};
  float cx=0.f,cy=0.f,cz=0.f, gx=0.f,gy=0.f,gz=0.f;

  bool staged = true;                    // first chunk already staged
  for (int base = n0; base < n1; base += 16){
    const int nc = min(16, n1 - base);
    if (!staged){
      if (lane < 32){
        if (lane*32 < nc*64){
          const uint4* src = (const uint4*)(edgeb + (size_t)base*16 + lane*8);
          *(uint4*)(sA + lane*32)      = src[0];
          *(uint4*)(sA + lane*32 + 16) = src[1];
        }
      } else if (lane < 48){
        int k = lane - 32;
        if (k < nc) *(float4*)(sE + k*4) = *(const float4*)(e4 + (size_t)(base+k)*4);
      } else {
        int k = lane - 48;
        if (k < nc) *(float4*)(sD + k*4) = *(const float4*)(dir4 + (size_t)(base+k)*4);
      }
    }
    staged = false;
    {
      short8 a0 = ld_frag(sA + l15*64 + quad*16);
      f32x4 accg[8];
      #pragma unroll
      for (int nf=0; nf<8; nf++){
        f32x4 z = (f32x4){0.f,0.f,0.f,0.f};
        accg[nf] = mfma16(a0, b4[nf], z);
      }
      #pragma unroll
      for (int reg=0; reg<4; reg++){
        int row = quad*4 + reg;
        uint4 o = make_uint4(pack2(accg[0][reg],accg[1][reg]),
                             pack2(accg[2][reg],accg[3][reg]),
                             pack2(accg[4][reg],accg[5][reg]),
                             pack2(accg[6][reg],accg[7][reg]));
        *(uint4*)(gC + row*256 + l15*16) = o;
      }
    }
    for (int t0 = 0; t0 < nc; t0 += 2){
      const int rloc = t0 + half;
      const bool act = rloc < nc;
      const int rc = act ? rloc : 0;
      const float4 ev = *(const float4*)(sE + rc*4);
      const float4 dv = *(const float4*)(sD + rc*4);
      const float aw0 = ev.x*i0, aw1 = ev.y*i1, aw2 = ev.z*i2, aw3 = ev.w*i3;
      uint2 gv = *(const uint2*)(gC + rc*256 + c*8);
      float g0=u2f(gv.x<<16), g1=u2f(gv.x&0xffff0000u);
      float g2=u2f(gv.y<<16), g3=u2f(gv.y&0xffff0000u);
      float tp = aw0*g0 + aw1*g1 + aw2*g2 + aw3*g3;
      float tt = fminf(fmaxf(tp, -15.f), 15.f);
      float ex = __expf(2.f*tt);
      float th = (ex-1.f)*frcp(ex+1.f);
      unsigned int ew = *(const unsigned int*)(sA + rc*64 + (c>>1)*4);
      float ec = (c & 1) ? u2f(ew & 0xffff0000u) : u2f(ew << 16);
      if (act){
        sem4[0] += ec*aw0; sem4[1] += ec*aw1;
        sem4[2] += ec*aw2; sem4[3] += ec*aw3;
        cx += th*dv.x; cy += th*dv.y; cz += th*dv.z;
        float tw = th*wvm_c;
        gx += tw*dv.x; gy += tw*dv.y; gz += tw*dv.z;
      }
    }
  }

  #pragma unroll
  for (int j=0;j<4;j++) sem4[j] += __shfl_xor(sem4[j], 32);
  cx += __shfl_xor(cx,32); cy += __shfl_xor(cy,32); cz += __shfl_xor(cz,32);
  #pragma unroll
  for (int off=32; off>=1; off>>=1){
    gx += __shfl_xor(gx,off); gy += __shfl_xor(gy,off); gz += __shfl_xor(gz,off);
  }
  const float invc = frcp((float)(cnt > 1 ? cnt : 1));
  if (low){
    float mx = cx*invc, my = cy*invc, mz = cz*invc;
    float n2v = mx*mx + my*my + mz*mz;
    float n2o = __shfl_xor(n2v, 1);
    if ((c & 1) == 0) n2B[(size_t)i*16 + (c>>1)] = pack2(n2v, n2o);
    *(uint2*)(semB + (size_t)i*64 + c*2) =
        make_uint2(pack2(sem4[0],sem4[1]), pack2(sem4[2],sem4[3]));
  }
  if (lane == 0)
    *(float4*)(wsDv + (size_t)i*4) = make_float4(gx*invc, gy*invc, gz*invc, 0.f);
}

// ---------------- node MLP v4 (r13 proven: 257.1us total): 2-way column split ------
// r15 lesson: 4-way split overshot (1-2 MFMAs per barrier interval -> barrier-
// dominated, +5.9us). The sweet spot is 2 waves / 16 rows.
__global__ __launch_bounds__(128) void k_mlp(
    const float* __restrict__ h, const float* __restrict__ x, const float* __restrict__ v,
    const unsigned short* __restrict__ hb,
    const unsigned short* __restrict__ semB, const unsigned short* __restrict__ n2B,
    const float* __restrict__ wsDv,
    const unsigned short* __restrict__ wb5, const unsigned short* __restrict__ wb6,
    const unsigned short* __restrict__ wb7, const unsigned short* __restrict__ wb8,
    const unsigned short* __restrict__ wb9,
    const float* __restrict__ bpn1, const float* __restrict__ bpn2,
    const float* __restrict__ bn1,  const float* __restrict__ bn2,
    const float* __restrict__ bv1,  const float* __restrict__ Wv2,
    float* __restrict__ out)
{
  __shared__ __align__(16) unsigned char sT[16*136];   // intermediate A (S1 out, N1 out)
  __shared__ __align__(16) unsigned char sU[16*136];   // intermediate B (S2 out, hnew)
  __shared__ float sPart[2*16];                        // V1 cross-wave combine

  const int tid  = threadIdx.x;
  const int wv   = tid >> 6;          // 0,1: owns nf {2wv, 2wv+1}
  const int lane = tid & 63;
  const int l15  = lane & 15;
  const int quad = lane >> 4;
  const int base = blockIdx.x*16;
  const int r0a  = min(base + l15, N_-1);
  const unsigned char* hB  = (const unsigned char*)hb;
  const unsigned char* sB  = (const unsigned char*)semB;
  const unsigned char* nB  = (const unsigned char*)n2B;

  // ---- S1: n2 [16 x 32] @ wb5 -> silu -> sT (cols 32wv..32wv+32) ----
  {
    f32x4 acc[2];
    #pragma unroll
    for (int nfh=0; nfh<2; nfh++){
      int nf = 2*wv + nfh;
      float b = bpn1[16*nf+l15]; acc[nfh] = (f32x4){b,b,b,b};
    }
    short8 a0 = ld_frag(nB + (size_t)r0a*64 + quad*16);
    #pragma unroll
    for (int nfh=0; nfh<2; nfh++){
      int nf = 2*wv + nfh;
      short8 b = ld_frag((const unsigned char*)wb5 + (size_t)(nf*64 + lane)*16);
      acc[nfh] = mfma16(a0, b, acc[nfh]);
    }
    #pragma unroll
    for (int nfh=0; nfh<2; nfh++){
      int n = 16*(2*wv+nfh) + l15;
      #pragma unroll
      for (int reg=0; reg<4; reg++){
        int row = quad*4 + reg;
        ((unsigned short*)(sT + row*136))[n] = (unsigned short)f2b16(silu_f(acc[nfh][reg]));
      }
    }
  }
  __syncthreads();
  // ---- S2: sT [16 x 64] @ wb6 -> silu -> sU ----
  {
    f32x4 acc[2];
    #pragma unroll
    for (int nfh=0; nfh<2; nfh++){
      int nf = 2*wv + nfh;
      float b = bpn2[16*nf+l15]; acc[nfh] = (f32x4){b,b,b,b};
    }
    #pragma unroll
    for (int s=0; s<2; s++){
      int koff = s*32 + quad*8;
      short8 a0 = ld_frag(sT + l15*136 + koff*2);
      #pragma unroll
      for (int nfh=0; nfh<2; nfh++){
        int nf = 2*wv + nfh;
        short8 b = ld_frag((const unsigned char*)wb6 + (size_t)((nf*2 + s)*64 + lane)*16);
        acc[nfh] = mfma16(a0, b, acc[nfh]);
      }
    }
    __syncthreads();   // all sT reads done before N1 overwrites sT later; also order sU writes
    #pragma unroll
    for (int nfh=0; nfh<2; nfh++){
      int n = 16*(2*wv+nfh) + l15;
      #pragma unroll
      for (int reg=0; reg<4; reg++){
        int row = quad*4 + reg;
        ((unsigned short*)(sU + row*136))[n] = (unsigned short)f2b16(silu_f(acc[nfh][reg]));
      }
    }
  }
  __syncthreads();
  // ---- N1 (K=256): [h | sem | sp] @ wb7 -> silu -> sT ----
  {
    f32x4 acc[2];
    #pragma unroll
    for (int nfh=0; nfh<2; nfh++){
      int nf = 2*wv + nfh;
      float b = bn1[16*nf+l15]; acc[nfh] = (f32x4){b,b,b,b};
    }
    #pragma unroll
    for (int s=0; s<8; s++){
      int koff = s*32 + quad*8;
      short8 a0;
      if (koff < 64){
        a0 = ld_frag(hB + (size_t)r0a*128 + koff*2);
      } else if (koff < 192){
        a0 = ld_frag(sB + (size_t)r0a*256 + (koff-64)*2);
      } else {
        a0 = ld_frag(sU + l15*136 + (koff-192)*2);
      }
      #pragma unroll
      for (int nfh=0; nfh<2; nfh++){
        int nf = 2*wv + nfh;
        short8 b = ld_frag((const unsigned char*)wb7 + (size_t)((nf*8 + s)*64 + lane)*16);
        acc[nfh] = mfma16(a0, b, acc[nfh]);
      }
    }
    #pragma unroll
    for (int nfh=0; nfh<2; nfh++){
      int n = 16*(2*wv+nfh) + l15;
      #pragma unroll
      for (int reg=0; reg<4; reg++){
        int row = quad*4 + reg;
        ((unsigned short*)(sT + row*136))[n] = (unsigned short)f2b16(silu_f(acc[nfh][reg]));
      }
    }
  }
  __syncthreads();
  // ---- N2 + residual: sT @ wb8 -> out (own cols), hnew -> sU ----
  {
    f32x4 acc[2];
    #pragma unroll
    for (int nfh=0; nfh<2; nfh++){
      int nf = 2*wv + nfh;
      float b = bn2[16*nf+l15]; acc[nfh] = (f32x4){b,b,b,b};
    }
    #pragma unroll
    for (int s=0; s<2; s++){
      int koff = s*32 + quad*8;
      short8 a0 = ld_frag(sT + l15*136 + koff*2);
      #pragma unroll
      for (int nfh=0; nfh<2; nfh++){
        int nf = 2*wv + nfh;
        short8 b = ld_frag((const unsigned char*)wb8 + (size_t)((nf*2 + s)*64 + lane)*16);
        acc[nfh] = mfma16(a0, b, acc[nfh]);
      }
    }
    #pragma unroll
    for (int nfh=0; nfh<2; nfh++){
      int n = 16*(2*wv+nfh) + l15;
      #pragma unroll
      for (int reg=0; reg<4; reg++){
        int row = quad*4 + reg;
        int node = base + row;
        float hv = (node < N_) ? h[(size_t)node*64 + n] : 0.f;
        float hnew = hv + silu_f(acc[nfh][reg]);
        if (node < N_) out[(size_t)node*64 + n] = hnew;
        ((unsigned short*)(sU + row*136))[n] = (unsigned short)f2b16(hnew);
      }
    }
  }
  __syncthreads();
  // ---- V1 + gate + v/x ----
  {
    f32x4 acc[2];
    #pragma unroll
    for (int nfh=0; nfh<2; nfh++){
      int nf = 2*wv + nfh;
      float b = bv1[16*nf+l15]; acc[nfh] = (f32x4){b,b,b,b};
    }
    #pragma unroll
    for (int s=0; s<2; s++){
      int koff = s*32 + quad*8;
      short8 a0 = ld_frag(sU + l15*136 + koff*2);
      #pragma unroll
      for (int nfh=0; nfh<2; nfh++){
        int nf = 2*wv + nfh;
        short8 b = ld_frag((const unsigned char*)wb9 + (size_t)((nf*2 + s)*64 + lane)*16);
        acc[nfh] = mfma16(a0, b, acc[nfh]);
      }
    }
    float part[4] = {0.f,0.f,0.f,0.f};
    #pragma unroll
    for (int nfh=0; nfh<2; nfh++){
      int nf = 2*wv + nfh;
      float w2 = Wv2[16*nf + l15];
      #pragma unroll
      for (int reg=0; reg<4; reg++)
        part[reg] += silu_f(acc[nfh][reg]) * w2;
    }
    #pragma unroll
    for (int reg=0; reg<4; reg++){
      #pragma unroll
      for (int off=1; off<16; off<<=1)
        part[reg] += __shfl_xor(part[reg], off);
    }
    if (l15 == 0){
      #pragma unroll
      for (int reg=0; reg<4; reg++)
        sPart[wv*16 + quad*4 + reg] = part[reg];
    }
    __syncthreads();
    if (wv == 0 && l15 == 0){
      #pragma unroll
      for (int reg=0; reg<4; reg++){
        int row = quad*4 + reg;
        int node = base + row;
        if (node < N_){
          float p = sPart[row] + sPart[16 + row];
          float gate = 2.f*frcp(1.f + __expf(-p));
          float4 dvv = *(const float4*)(wsDv + (size_t)node*4);
          float dvs[3] = {dvv.x, dvv.y, dvv.z};
          #pragma unroll
          for (int ax=0; ax<3; ax++){
            float vn = gate * v[(size_t)node*3 + ax] + dvs[ax];
            out[(size_t)N_*64 + (size_t)node*3 + ax]                 = x[(size_t)node*3 + ax] + vn;
            out[(size_t)N_*64 + (size_t)N_*3 + (size_t)node*3 + ax]  = vn;
          }
        }
      }
    }
  }
}

// ---------------- launch ----------------
extern "C" void kernel_launch(void* const* d_in, const int* in_sizes, int n_in,
                              void* d_out, int out_size, void* d_ws, size_t ws_size,
                              hipStream_t stream)
{
  const float* h = (const float*)d_in[0];
  const float* x = (const float*)d_in[1];
  const float* v = (const float*)d_in[2];
  const int* idx_i = (const int*)d_in[3];
  const int* idx_j = (const int*)d_in[4];
  const float* Wein = (const float*)d_in[5];  const float* bein = (const float*)d_in[6];
  const float* Weo1 = (const float*)d_in[7];  const float* beo1 = (const float*)d_in[8];
  const float* Weo2 = (const float*)d_in[9];  const float* beo2 = (const float*)d_in[10];
  const float* Watt = (const float*)d_in[11]; const float* batt = (const float*)d_in[12];
  const float* Wxm  = (const float*)d_in[13]; const float* Wvm  = (const float*)d_in[14];
  const float* Wpn1 = (const float*)d_in[15]; const float* bpn1 = (const float*)d_in[16];
  const float* Wpn2 = (const float*)d_in[17]; const float* bpn2 = (const float*)d_in[18];
  const float* Wn1  = (const float*)d_in[19]; const float* bn1  = (const float*)d_in[20];
  const float* Wn2  = (const float*)d_in[21]; const float* bn2  = (const float*)d_in[22];
  const float* Wv1  = (const float*)d_in[23]; const float* bv1  = (const float*)d_in[24];
  const float* Wv2  = (const float*)d_in[25];

  float* wsf        = (float*)d_ws;
  int*   cnt        = (int*)(wsf + OFF_CNT);
  int*   offsets    = (int*)(wsf + OFF_OFFSETS);
  unsigned int* edgeb = (unsigned int*)(wsf + OFF_EDGE);
  float* e4o        = wsf + OFF_E4;
  float* diro       = wsf + OFF_DIR;
  unsigned int* semB = (unsigned int*)(wsf + OFF_SEM);
  unsigned int* n2B  = (unsigned int*)(wsf + OFF_N2);
  float* wsDv       = wsf + OFF_DV;
  unsigned short* wb1 = (unsigned short*)(wsf + OFF_WB1);
  unsigned short* wb2 = (unsigned short*)(wsf + OFF_WB2);
  unsigned short* wb3 = (unsigned short*)(wsf + OFF_WB3);
  unsigned short* wb4 = (unsigned short*)(wsf + OFF_WB4);
  unsigned short* wb5 = (unsigned short*)(wsf + OFF_WB5);
  unsigned short* wb6 = (unsigned short*)(wsf + OFF_WB6);
  unsigned short* wb7 = (unsigned short*)(wsf + OFF_WB7);
  unsigned short* wb8 = (unsigned short*)(wsf + OFF_WB8);
  unsigned short* wb9 = (unsigned short*)(wsf + OFF_WB9);
  unsigned int*   hb  = (unsigned int*)(wsf + OFF_HB);
  int*            sij = (int*)(wsf + OFF_SIJ);
  int*            rnk = (int*)(wsf + OFF_RANK);

  hipMemsetAsync(cnt, 0, N_*sizeof(int), stream);
  k_hist<<<(P_+255)/256, 256, 0, stream>>>(idx_i, cnt, rnk);
  k_scan2<<<65, 1024, 0, stream>>>(cnt, offsets, h,
                                   Wein, Weo1, Weo2, Wxm, Wpn1, Wpn2,
                                   Wn1, Wn2, Wv1,
                                   hb, wb1, wb2, wb3, wb4,
                                   wb5, wb6, wb7, wb8, wb9);
  k_scatter3<<<(P_+255)/256, 256, 0, stream>>>(idx_i, idx_j, offsets, rnk, sij);
  k_edge2<<<P_/128, 256, 0, stream>>>((const unsigned short*)hb, sij, x, diro,
                                      wb1, wb2, wb3,
                                      bein, beo1, beo2, Watt, batt,
                                      edgeb, e4o);
  k_agg<<<(N_+3)/4, 256, 0, stream>>>(offsets, edgeb, e4o, diro, wb4, Wvm,
                                      semB, n2B, wsDv);
  k_mlp<<<(N_+15)/16, 128, 0, stream>>>(h, x, v,
                                        (const unsigned short*)hb,
                                        (const unsigned short*)semB,
                                        (const unsigned short*)n2B,
                                        wsDv,
                                        wb5, wb6, wb7, wb8, wb9,
                                        bpn1, bpn2, bn1, bn2, bv1, Wv2,
                                        (float*)d_out);
}